// Round 1
// baseline (970.908 us; speedup 1.0000x reference)
//
#include <hip/hip_runtime.h>
#include <hip/hip_bf16.h>
#include <stdint.h>

#define NN 50000
#define NE 800000
#define DD 256
#define NL 4
#define NRL 4
#define KT 1280  // NRL*DD + DD (logical K of the fused GEMM)
#define KA 1024  // NRL*DD (columns stored in Abig; root block comes from Xbf)

typedef float f32x4 __attribute__((ext_vector_type(4)));
typedef __bf16 bf16x8 __attribute__((ext_vector_type(8)));
typedef __bf16 bf16x4 __attribute__((ext_vector_type(4)));
typedef unsigned short u16x4 __attribute__((ext_vector_type(4)));

static __device__ __forceinline__ unsigned short f2bf(float f) {
  __bf16 h = (__bf16)f;
  return __builtin_bit_cast(unsigned short, h);
}

static __device__ __forceinline__ u16x4 pk4(f32x4 v) {
  u16x4 o;
  o.x = f2bf(v.x); o.y = f2bf(v.y); o.z = f2bf(v.z); o.w = f2bf(v.w);
  return o;
}

static __device__ __forceinline__ void async16(const void* g, void* l) {
  __builtin_amdgcn_global_load_lds(
      (const __attribute__((address_space(1))) unsigned int*)g,
      (__attribute__((address_space(3))) unsigned int*)l, 16, 0, 0);
}

// nt-hint variant (aux bit1 = NT on gfx94x/gfx950): stream, don't allocate in cache
static __device__ __forceinline__ void async16nt(const void* g, void* l) {
  __builtin_amdgcn_global_load_lds(
      (const __attribute__((address_space(1))) unsigned int*)g,
      (__attribute__((address_space(3))) unsigned int*)l, 16, 0, 2);
}

// ---------------- edge preprocessing (once per call) ----------------

__global__ __launch_bounds__(256) void k_hist(const int* __restrict__ ei,
                                              const int* __restrict__ et,
                                              int* __restrict__ cntNR) {
  int e = blockIdx.x * 256 + threadIdx.x;
  if (e >= NE) return;
  int dst = ei[NE + e];
  int r = et[e];
  atomicAdd(&cntNR[dst * 4 + r], 1);
}

__global__ __launch_bounds__(256) void k_scan1(const int* __restrict__ cntNR,
                                               int* __restrict__ offs,
                                               int* __restrict__ bsum) {
  __shared__ int sd[256];
  const int t = threadIdx.x;
  const int n = blockIdx.x * 256 + t;
  int deg = 0;
  if (n < NN) {
    const int* c = cntNR + n * 4;
    deg = c[0] + c[1] + c[2] + c[3];
  }
  sd[t] = deg;
  __syncthreads();
  int val = deg;
  for (int d = 1; d < 256; d <<= 1) {
    int other = (t >= d) ? sd[t - d] : 0;
    __syncthreads();
    val += other;
    sd[t] = val;
    __syncthreads();
  }
  if (n < NN) offs[n] = val - deg;  // exclusive
  if (t == 255) bsum[blockIdx.x] = val;
}

__global__ __launch_bounds__(256) void k_scan2(const int* __restrict__ bsum,
                                               int* __restrict__ boff, int nb) {
  __shared__ int sd[256];
  const int t = threadIdx.x;
  int v = (t < nb) ? bsum[t] : 0;
  sd[t] = v;
  __syncthreads();
  int val = v;
  for (int d = 1; d < 256; d <<= 1) {
    int other = (t >= d) ? sd[t - d] : 0;
    __syncthreads();
    val += other;
    sd[t] = val;
    __syncthreads();
  }
  boff[t] = val - v;  // exclusive
}

__global__ __launch_bounds__(256) void k_scan3(int* __restrict__ offs,
                                               const int* __restrict__ boff,
                                               int* __restrict__ cursor) {
  int n = blockIdx.x * 256 + threadIdx.x;
  if (n < NN) {
    int o = offs[n] + boff[blockIdx.x];
    offs[n] = o;
    cursor[n] = o;
  }
  if (n == 0) offs[NN] = NE;
}

__global__ __launch_bounds__(256) void k_scatter(const int* __restrict__ ei,
                                                 const int* __restrict__ et,
                                                 int* __restrict__ cursor,
                                                 uint32_t* __restrict__ packed) {
  int e = blockIdx.x * 256 + threadIdx.x;
  if (e >= NE) return;
  int src = ei[e];
  int dst = ei[NE + e];
  int r = et[e];
  int pos = atomicAdd(&cursor[dst], 1);
  packed[pos] = (uint32_t)src | ((uint32_t)r << 16);  // src < 65536 ok
}

// Build WbigT[l][o][k] bf16: k<1024 -> weights[l][k>>8][k&255][o], else roots[l][k-1024][o]
__global__ __launch_bounds__(256) void k_wconv(const float* __restrict__ weights,
                                               const float* __restrict__ roots,
                                               __hip_bfloat16* __restrict__ WbigT) {
  int idx = blockIdx.x * 256 + threadIdx.x;
  if (idx >= NL * DD * KT) return;
  int l = idx / (DD * KT);
  int rem = idx - l * (DD * KT);
  int o = rem / KT;
  int k = rem - o * KT;
  float v;
  if (k < NRL * DD) {
    int r = k >> 8, i = k & 255;
    v = weights[(((size_t)(l * NRL + r) * DD) + i) * DD + o];
  } else {
    int i = k - NRL * DD;
    v = roots[((size_t)l * DD + i) * DD + o];
  }
  WbigT[idx] = __float2bfloat16(v);
}

// one-time fp32 -> bf16 cast of the input embedding (4 elems/thread)
__global__ __launch_bounds__(256) void k_cast(const float* __restrict__ X,
                                              __hip_bfloat16* __restrict__ Xbf) {
  int i = blockIdx.x * 256 + threadIdx.x;
  if (i >= NN * 64) return;
  const f32x4* Xv = (const f32x4*)X;
  ((u16x4*)Xbf)[i] = pk4(Xv[i]);
}

// ---------------- per-layer aggregation: one wave per node, pipelined bf16 gather ------

__global__ __launch_bounds__(256) void k_agg(const __hip_bfloat16* __restrict__ Xbf,
                                             const uint32_t* __restrict__ packed,
                                             const int* __restrict__ offs,
                                             const int* __restrict__ cntNR,
                                             __hip_bfloat16* __restrict__ Abig) {
  const int wid = (blockIdx.x * 256 + threadIdx.x) >> 6;
  const int lane = threadIdx.x & 63;
  if (wid >= NN) return;
  const int beg = offs[wid];
  const int end = offs[wid + 1];
  const bf16x4* __restrict__ Xv = (const bf16x4*)Xbf;

  f32x4 a0 = {0.f, 0.f, 0.f, 0.f}, a1 = a0, a2 = a0, a3 = a0;

  // depth-8 software pipeline: 8 packed loads, then 8 row-gathers in flight,
  // then accumulate (r is wave-uniform -> scalar branch)
  for (int e = beg; e < end; e += 8) {
    uint32_t pv[8];
    bf16x4 vv[8];
#pragma unroll
    for (int i = 0; i < 8; ++i) {
      int ee = e + i;
      ee = (ee < end) ? ee : (end - 1);
      pv[i] = packed[ee];
    }
#pragma unroll
    for (int i = 0; i < 8; ++i) {
      vv[i] = Xv[(int)(pv[i] & 0xFFFFu) * 64 + lane];
    }
    const int nv = end - e;
#pragma unroll
    for (int i = 0; i < 8; ++i) {
      if (i < nv) {
        int r = (int)(pv[i] >> 16);
        f32x4 v = {(float)vv[i][0], (float)vv[i][1], (float)vv[i][2], (float)vv[i][3]};
        if (r == 0) a0 += v;
        else if (r == 1) a1 += v;
        else if (r == 2) a2 += v;
        else a3 += v;
      }
    }
  }

  const int* c = cntNR + wid * 4;
  int c0 = c[0], c1 = c[1], c2 = c[2], c3 = c[3];
  float s0 = 1.0f / (float)(c0 > 1 ? c0 : 1);
  float s1 = 1.0f / (float)(c1 > 1 ? c1 : 1);
  float s2 = 1.0f / (float)(c2 > 1 ? c2 : 1);
  float s3 = 1.0f / (float)(c3 > 1 ? c3 : 1);

  // nt stores: don't let the 100MB Abig stream evict Xbf from L3
  u16x4* Arow = (u16x4*)(Abig + (size_t)wid * KA);
  __builtin_nontemporal_store(pk4(a0 * s0), Arow + 0 * 64 + lane);
  __builtin_nontemporal_store(pk4(a1 * s1), Arow + 1 * 64 + lane);
  __builtin_nontemporal_store(pk4(a2 * s2), Arow + 2 * 64 + lane);
  __builtin_nontemporal_store(pk4(a3 * s3), Arow + 3 * 64 + lane);
}

// ---------------- GEMM + bias + LayerNorm + ELU + residual (+ bf16 X for next layer) ----
// C[m, n] = [Abig | Xbf][m, 0:1280] @ WbigT[n, 0:1280]^T ; BM=64, BN=256, BK=32
// 4 waves in 2x2: each wave 32 rows x 128 cols = 2x8 MFMA tiles.
// 3-buffer LDS pipeline, counted vmcnt(5) + raw s_barrier (T3+T4 minimum):
// loads for tile t+1 stay in flight across the barrier; never drain vmcnt to 0
// in the main loop.  Per wave per tile: 1 A + 4 B global_load_lds = 5 vmem ops.

#define GBUF 20480  // per-buffer LDS bytes: A 4KB + B 16KB
#define NTILE 40    // KT*2/64

__global__ __launch_bounds__(256, 2) void k_gemm(const __hip_bfloat16* __restrict__ A,
                                                 const __hip_bfloat16* __restrict__ Xbf_in,
                                                 const __hip_bfloat16* __restrict__ Bt,
                                                 const float* __restrict__ bias,
                                                 const float* __restrict__ gamma,
                                                 const float* __restrict__ beta,
                                                 const float* __restrict__ Xin,
                                                 float* __restrict__ Xout,
                                                 __hip_bfloat16* __restrict__ Xbf_out) {
  __shared__ __align__(16) char sLDS[3 * GBUF];  // 60KB: 3 x (A 64x64B | B 256x64B)
  __shared__ float sRed[64][4];

  const int tid = threadIdx.x;
  const int w = tid >> 6;
  const int lane = tid & 63;
  const int wm = w >> 1, wn = w & 1;
  const int quad = lane >> 4, l15 = lane & 15;
  const int mBase = blockIdx.x * 64;

  // staging lane map: lane i -> row i/4, LDS slot i%4; global chunk = slot ^ ((row>>1)&3)
  const int srow = lane >> 2;
  const int kc = (lane & 3) ^ ((srow >> 1) & 3);

  int am = mBase + w * 16 + srow;
  if (am >= NN) am = NN - 1;  // clamp (stores are guarded)
  const char* agp = (const char*)A + (size_t)am * (KA * 2) + kc * 16;
  const char* agx = (const char*)Xbf_in + (size_t)am * (DD * 2) + kc * 16;
  const char* bgp0 = (const char*)Bt + (size_t)(w * 64 + 0 + srow) * (KT * 2) + kc * 16;
  const char* bgp1 = (const char*)Bt + (size_t)(w * 64 + 16 + srow) * (KT * 2) + kc * 16;
  const char* bgp2 = (const char*)Bt + (size_t)(w * 64 + 32 + srow) * (KT * 2) + kc * 16;
  const char* bgp3 = (const char*)Bt + (size_t)(w * 64 + 48 + srow) * (KT * 2) + kc * 16;

  // per-wave LDS staging bases (wave-uniform; lane deposits at base + lane*16)
  char* const lA = sLDS + w * 1024;
  char* const lB = sLDS + 4096 + w * 4096;

  f32x4 acc[2][8];
#pragma unroll
  for (int i = 0; i < 2; ++i)
#pragma unroll
    for (int j = 0; j < 8; ++j) acc[i][j] = (f32x4){0.f, 0.f, 0.f, 0.f};

  const int aslot = (quad ^ ((l15 >> 1) & 3)) * 16;
  const char* const aBase = sLDS + (wm * 32 + l15) * 64 + aslot;          // + buf*GBUF + mt*1024
  const char* const bBase = sLDS + 4096 + (wn * 128 + l15) * 64 + aslot;  // + buf*GBUF + nt*1024

  auto STAGE = [&](int buf, int ts) {
    const int k0 = ts * 64;  // byte offset within logical K row
    char* la = lA + buf * GBUF;
    char* lb = lB + buf * GBUF;
    if (k0 < KA * 2) {  // cols 0..1023 from Abig (nt: read once, don't pollute L3)
      async16nt(agp + k0, la);
    } else {            // cols 1024..1279 from Xbf (keep cached)
      async16(agx + (k0 - KA * 2), la);
    }
    async16(bgp0 + k0, lb);
    async16(bgp1 + k0, lb + 1024);
    async16(bgp2 + k0, lb + 2048);
    async16(bgp3 + k0, lb + 3072);
  };

  STAGE(0, 0);  // prologue: tile 0 in flight (5 vmem ops/wave)
  int cb = 0, sb = 1;
  for (int t = 0; t < NTILE; ++t) {
    // stage next tile (last iter re-stages tile 39 into an unread buffer so the
    // vmcnt arithmetic stays constant; data is never consumed)
    const int ts = (t + 1 < NTILE) ? (t + 1) : (NTILE - 1);
    STAGE(sb, ts);
    __builtin_amdgcn_sched_barrier(0);
    // wait for tile t only (5 newest = tile t+1 may stay in flight across barrier)
    asm volatile("s_waitcnt vmcnt(5)" ::: "memory");
    __builtin_amdgcn_s_barrier();
    __builtin_amdgcn_sched_barrier(0);

    const char* aAddr = aBase + cb * GBUF;
    const char* bAddr = bBase + cb * GBUF;
    bf16x8 a0 = *(const bf16x8*)(aAddr + 0 * 1024);
    bf16x8 a1 = *(const bf16x8*)(aAddr + 1 * 1024);
#pragma unroll
    for (int nt = 0; nt < 8; ++nt) {
      bf16x8 b = *(const bf16x8*)(bAddr + nt * 1024);
      acc[0][nt] = __builtin_amdgcn_mfma_f32_16x16x32_bf16(a0, b, acc[0][nt], 0, 0, 0);
      acc[1][nt] = __builtin_amdgcn_mfma_f32_16x16x32_bf16(a1, b, acc[1][nt], 0, 0, 0);
    }
    cb = (cb == 2) ? 0 : cb + 1;
    sb = (sb == 2) ? 0 : sb + 1;
  }

  // ---- epilogue: bias, LN (full 256-wide rows in-block), ELU, residual ----
  float bv[8], gv[8], bev[8];
#pragma unroll
  for (int nt = 0; nt < 8; ++nt) {
    int n = wn * 128 + nt * 16 + l15;
    bv[nt] = bias[n];
    gv[nt] = gamma[n];
    bev[nt] = beta[n];
  }

#pragma unroll
  for (int mt = 0; mt < 2; ++mt) {
#pragma unroll
    for (int reg = 0; reg < 4; ++reg) {
      float s = 0.f, q = 0.f;
#pragma unroll
      for (int nt = 0; nt < 8; ++nt) {
        float v = acc[mt][nt][reg] + bv[nt];
        acc[mt][nt][reg] = v;
        s += v;
        q += v * v;
      }
#pragma unroll
      for (int d = 1; d < 16; d <<= 1) {
        s += __shfl_xor(s, d, 64);
        q += __shfl_xor(q, d, 64);
      }
      if (l15 == 0) {
        int row = wm * 32 + mt * 16 + quad * 4 + reg;
        sRed[row][wn * 2] = s;
        sRed[row][wn * 2 + 1] = q;
      }
    }
  }
  __syncthreads();

#pragma unroll
  for (int mt = 0; mt < 2; ++mt) {
#pragma unroll
    for (int reg = 0; reg < 4; ++reg) {
      int row = wm * 32 + mt * 16 + quad * 4 + reg;
      float ts = sRed[row][0] + sRed[row][2];
      float tq = sRed[row][1] + sRed[row][3];
      float mean = ts * (1.0f / 256.0f);
      float var = tq * (1.0f / 256.0f) - mean * mean;
      float rstd = rsqrtf(var + 1e-5f);
      int m = mBase + row;
      if (m < NN) {
#pragma unroll
        for (int nt = 0; nt < 8; ++nt) {
          int n = wn * 128 + nt * 16 + l15;
          float v = (acc[mt][nt][reg] - mean) * rstd * gv[nt] + bev[nt];
          v = v > 0.0f ? v : (__expf(v) - 1.0f);
          float res = v + Xin[(size_t)m * 256 + n];
          Xout[(size_t)m * 256 + n] = res;
          Xbf_out[(size_t)m * 256 + n] = __float2bfloat16(res);
        }
      }
    }
  }
}

// ---------------- host side ----------------

extern "C" void kernel_launch(void* const* d_in, const int* in_sizes, int n_in,
                              void* d_out, int out_size, void* d_ws, size_t ws_size,
                              hipStream_t stream) {
  const float* X0 = (const float*)d_in[0];
  const float* weights = (const float*)d_in[1];
  const float* roots = (const float*)d_in[2];
  const float* biases = (const float*)d_in[3];
  const float* ln_g = (const float*)d_in[4];
  const float* ln_b = (const float*)d_in[5];
  const int* eidx = (const int*)d_in[6];
  const int* etyp = (const int*)d_in[7];
  float* out = (float*)d_out;

  char* ws = (char*)d_ws;
  size_t off = 0;
  auto alloc = [&](size_t bytes) -> char* {
    char* p = ws + off;
    off = (off + bytes + 255) & ~(size_t)255;
    return p;
  };
  __hip_bfloat16* Abig = (__hip_bfloat16*)alloc((size_t)NN * KA * 2);          // 102.4 MB
  __hip_bfloat16* WbigT = (__hip_bfloat16*)alloc((size_t)NL * DD * KT * 2);    // 2.6 MB
  float* Xb0 = (float*)alloc((size_t)NN * DD * 4);                              // 51.2 MB
  float* Xb1 = (float*)alloc((size_t)NN * DD * 4);                              // 51.2 MB
  __hip_bfloat16* Xbf0 = (__hip_bfloat16*)alloc((size_t)NN * DD * 2);           // 25.6 MB
  __hip_bfloat16* Xbf1 = (__hip_bfloat16*)alloc((size_t)NN * DD * 2);           // 25.6 MB
  int* cntNR = (int*)alloc((size_t)NN * 4 * 4);
  int* offs = (int*)alloc((size_t)(NN + 1) * 4);
  int* cursor = (int*)alloc((size_t)NN * 4);
  uint32_t* packed = (uint32_t*)alloc((size_t)NE * 4);
  int* bsum = (int*)alloc(256 * 4);
  int* boff = (int*)alloc(256 * 4);
  (void)ws_size; (void)in_sizes; (void)n_in; (void)out_size;

  (void)hipMemsetAsync(cntNR, 0, (size_t)NN * 16, stream);
  k_hist<<<(NE + 255) / 256, 256, 0, stream>>>(eidx, etyp, cntNR);
  const int NB = (NN + 255) / 256;  // 196
  k_scan1<<<NB, 256, 0, stream>>>(cntNR, offs, bsum);
  k_scan2<<<1, 256, 0, stream>>>(bsum, boff, NB);
  k_scan3<<<NB, 256, 0, stream>>>(offs, boff, cursor);
  k_scatter<<<(NE + 255) / 256, 256, 0, stream>>>(eidx, etyp, cursor, packed);
  k_wconv<<<(NL * DD * KT + 255) / 256, 256, 0, stream>>>(weights, roots, WbigT);
  k_cast<<<(NN * 64 + 255) / 256, 256, 0, stream>>>(X0, Xbf0);

  const float* Xin = X0;
  for (int l = 0; l < NL; ++l) {
    float* Xout = (l == NL - 1) ? out : ((l & 1) ? Xb1 : Xb0);
    const __hip_bfloat16* Xbin = (l & 1) ? Xbf1 : Xbf0;
    __hip_bfloat16* Xbout = (l & 1) ? Xbf0 : Xbf1;
    k_agg<<<(NN * 64 + 255) / 256, 256, 0, stream>>>(Xbin, packed, offs, cntNR, Abig);
    k_gemm<<<(NN + 63) / 64, 256, 0, stream>>>(Abig, Xbin,
                                               WbigT + (size_t)l * DD * KT,
                                               biases + (size_t)l * DD,
                                               ln_g + (size_t)l * DD,
                                               ln_b + (size_t)l * DD, Xin, Xout, Xbout);
    Xin = Xout;
  }
}

// Round 2
// 866.414 us; speedup vs baseline: 1.1206x; 1.1206x over previous
//
#include <hip/hip_runtime.h>
#include <hip/hip_bf16.h>
#include <stdint.h>

#define NN 50000
#define NE 800000
#define DD 256
#define NL 4
#define NRL 4
#define KT 1280  // NRL*DD + DD (logical K of the fused GEMM)
#define KA 1024  // NRL*DD (columns stored in Abig; root block comes from Xbf)

typedef float f32x4 __attribute__((ext_vector_type(4)));
typedef __bf16 bf16x8 __attribute__((ext_vector_type(8)));
typedef __bf16 bf16x4 __attribute__((ext_vector_type(4)));
typedef unsigned short u16x4 __attribute__((ext_vector_type(4)));

static __device__ __forceinline__ unsigned short f2bf(float f) {
  __bf16 h = (__bf16)f;
  return __builtin_bit_cast(unsigned short, h);
}

static __device__ __forceinline__ u16x4 pk4(f32x4 v) {
  u16x4 o;
  o.x = f2bf(v.x); o.y = f2bf(v.y); o.z = f2bf(v.z); o.w = f2bf(v.w);
  return o;
}

static __device__ __forceinline__ void async16(const void* g, void* l) {
  __builtin_amdgcn_global_load_lds(
      (const __attribute__((address_space(1))) unsigned int*)g,
      (__attribute__((address_space(3))) unsigned int*)l, 16, 0, 0);
}

// ---------------- edge preprocessing (once per call) ----------------

__global__ __launch_bounds__(256) void k_hist(const int* __restrict__ ei,
                                              const int* __restrict__ et,
                                              int* __restrict__ cntNR) {
  int e = blockIdx.x * 256 + threadIdx.x;
  if (e >= NE) return;
  int dst = ei[NE + e];
  int r = et[e];
  atomicAdd(&cntNR[dst * 4 + r], 1);
}

__global__ __launch_bounds__(256) void k_scan1(const int* __restrict__ cntNR,
                                               int* __restrict__ offs,
                                               int* __restrict__ bsum) {
  __shared__ int sd[256];
  const int t = threadIdx.x;
  const int n = blockIdx.x * 256 + t;
  int deg = 0;
  if (n < NN) {
    const int* c = cntNR + n * 4;
    deg = c[0] + c[1] + c[2] + c[3];
  }
  sd[t] = deg;
  __syncthreads();
  int val = deg;
  for (int d = 1; d < 256; d <<= 1) {
    int other = (t >= d) ? sd[t - d] : 0;
    __syncthreads();
    val += other;
    sd[t] = val;
    __syncthreads();
  }
  if (n < NN) offs[n] = val - deg;  // exclusive
  if (t == 255) bsum[blockIdx.x] = val;
}

__global__ __launch_bounds__(256) void k_scan2(const int* __restrict__ bsum,
                                               int* __restrict__ boff, int nb) {
  __shared__ int sd[256];
  const int t = threadIdx.x;
  int v = (t < nb) ? bsum[t] : 0;
  sd[t] = v;
  __syncthreads();
  int val = v;
  for (int d = 1; d < 256; d <<= 1) {
    int other = (t >= d) ? sd[t - d] : 0;
    __syncthreads();
    val += other;
    sd[t] = val;
    __syncthreads();
  }
  boff[t] = val - v;  // exclusive
}

__global__ __launch_bounds__(256) void k_scan3(int* __restrict__ offs,
                                               const int* __restrict__ boff,
                                               int* __restrict__ cursor) {
  int n = blockIdx.x * 256 + threadIdx.x;
  if (n < NN) {
    int o = offs[n] + boff[blockIdx.x];
    offs[n] = o;
    cursor[n] = o;
  }
  if (n == 0) offs[NN] = NE;
}

__global__ __launch_bounds__(256) void k_scatter(const int* __restrict__ ei,
                                                 const int* __restrict__ et,
                                                 int* __restrict__ cursor,
                                                 uint32_t* __restrict__ packed) {
  int e = blockIdx.x * 256 + threadIdx.x;
  if (e >= NE) return;
  int src = ei[e];
  int dst = ei[NE + e];
  int r = et[e];
  int pos = atomicAdd(&cursor[dst], 1);
  packed[pos] = (uint32_t)src | ((uint32_t)r << 16);  // src < 65536 ok
}

// Build WbigT[l][o][k] bf16: k<1024 -> weights[l][k>>8][k&255][o], else roots[l][k-1024][o]
__global__ __launch_bounds__(256) void k_wconv(const float* __restrict__ weights,
                                               const float* __restrict__ roots,
                                               __hip_bfloat16* __restrict__ WbigT) {
  int idx = blockIdx.x * 256 + threadIdx.x;
  if (idx >= NL * DD * KT) return;
  int l = idx / (DD * KT);
  int rem = idx - l * (DD * KT);
  int o = rem / KT;
  int k = rem - o * KT;
  float v;
  if (k < NRL * DD) {
    int r = k >> 8, i = k & 255;
    v = weights[(((size_t)(l * NRL + r) * DD) + i) * DD + o];
  } else {
    int i = k - NRL * DD;
    v = roots[((size_t)l * DD + i) * DD + o];
  }
  WbigT[idx] = __float2bfloat16(v);
}

// one-time fp32 -> bf16 cast of the input embedding (4 elems/thread)
__global__ __launch_bounds__(256) void k_cast(const float* __restrict__ X,
                                              __hip_bfloat16* __restrict__ Xbf) {
  int i = blockIdx.x * 256 + threadIdx.x;
  if (i >= NN * 64) return;
  const f32x4* Xv = (const f32x4*)X;
  ((u16x4*)Xbf)[i] = pk4(Xv[i]);
}

// ---------------- per-layer aggregation: one wave per node, pipelined bf16 gather ------

__global__ __launch_bounds__(256) void k_agg(const __hip_bfloat16* __restrict__ Xbf,
                                             const uint32_t* __restrict__ packed,
                                             const int* __restrict__ offs,
                                             const int* __restrict__ cntNR,
                                             __hip_bfloat16* __restrict__ Abig) {
  const int wid = (blockIdx.x * 256 + threadIdx.x) >> 6;
  const int lane = threadIdx.x & 63;
  if (wid >= NN) return;
  const int beg = offs[wid];
  const int end = offs[wid + 1];
  const bf16x4* __restrict__ Xv = (const bf16x4*)Xbf;

  f32x4 a0 = {0.f, 0.f, 0.f, 0.f}, a1 = a0, a2 = a0, a3 = a0;

  // depth-8 software pipeline: 8 packed loads, then 8 row-gathers in flight,
  // then accumulate (r is wave-uniform -> scalar branch)
  for (int e = beg; e < end; e += 8) {
    uint32_t pv[8];
    bf16x4 vv[8];
#pragma unroll
    for (int i = 0; i < 8; ++i) {
      int ee = e + i;
      ee = (ee < end) ? ee : (end - 1);
      pv[i] = packed[ee];
    }
#pragma unroll
    for (int i = 0; i < 8; ++i) {
      vv[i] = Xv[(int)(pv[i] & 0xFFFFu) * 64 + lane];
    }
    const int nv = end - e;
#pragma unroll
    for (int i = 0; i < 8; ++i) {
      if (i < nv) {
        int r = (int)(pv[i] >> 16);
        f32x4 v = {(float)vv[i][0], (float)vv[i][1], (float)vv[i][2], (float)vv[i][3]};
        if (r == 0) a0 += v;
        else if (r == 1) a1 += v;
        else if (r == 2) a2 += v;
        else a3 += v;
      }
    }
  }

  const int* c = cntNR + wid * 4;
  int c0 = c[0], c1 = c[1], c2 = c[2], c3 = c[3];
  float s0 = 1.0f / (float)(c0 > 1 ? c0 : 1);
  float s1 = 1.0f / (float)(c1 > 1 ? c1 : 1);
  float s2 = 1.0f / (float)(c2 > 1 ? c2 : 1);
  float s3 = 1.0f / (float)(c3 > 1 ? c3 : 1);

  // CACHED stores: Abig is consumed by the immediately-following k_gemm.
  // It (102MB) + Xbf (2x25.6MB) + packed (3.2MB) fit in the 256MB L3; letting
  // it allocate means the GEMM A-reads are L3 hits and Abig never round-trips
  // HBM.  (The fp32 X streams are NT'd in k_gemm instead.)
  u16x4* Arow = (u16x4*)(Abig + (size_t)wid * KA);
  Arow[0 * 64 + lane] = pk4(a0 * s0);
  Arow[1 * 64 + lane] = pk4(a1 * s1);
  Arow[2 * 64 + lane] = pk4(a2 * s2);
  Arow[3 * 64 + lane] = pk4(a3 * s3);
}

// ---------------- GEMM + bias + LayerNorm + ELU + residual (+ bf16 X for next layer) ----
// C[m, n] = [Abig | Xbf][m, 0:1280] @ WbigT[n, 0:1280]^T ; BM=64, BN=256, BK=32
// 4 waves in 2x2: each wave 32 rows x 128 cols = 2x8 MFMA tiles.
// 4-buffer LDS pipeline, depth-2 prefetch with counted vmcnt (T3+T4):
//   steady state: tiles t, t+1, t+2 in flight (15 vmem ops/wave);
//   s_waitcnt vmcnt(10) retires tile t only.  Tail is peeled (vmcnt 5 then 0)
//   so the counts stay exact.  Per wave per tile: 1 A + 4 B loads = 5 vmem ops.
// Race rule: stage at iter t targets buf (t+2)%4, last computed at iter t-2;
// all waves passed barrier(t-1) after their compute(t-2) -> no overlap.
// sRed is overlaid on buf0's A-area (dead after the final barrier; no in-flight
// loads remain because the peeled tail drains vmcnt to 0).

#define GBUF 20480  // per-buffer LDS bytes: A 4KB + B 16KB
#define NTILE 40    // KT*2/64

__global__ __launch_bounds__(256, 2) void k_gemm(const __hip_bfloat16* __restrict__ A,
                                                 const __hip_bfloat16* __restrict__ Xbf_in,
                                                 const __hip_bfloat16* __restrict__ Bt,
                                                 const float* __restrict__ bias,
                                                 const float* __restrict__ gamma,
                                                 const float* __restrict__ beta,
                                                 const float* __restrict__ Xin,
                                                 float* __restrict__ Xout,
                                                 __hip_bfloat16* __restrict__ Xbf_out) {
  __shared__ __align__(16) char sLDS[4 * GBUF];  // 80KB: 4 x (A 64x64B | B 256x64B)
  float(*sRed)[4] = (float(*)[4])sLDS;           // overlay, used after the main loop

  const int tid = threadIdx.x;
  const int w = tid >> 6;
  const int lane = tid & 63;
  const int wm = w >> 1, wn = w & 1;
  const int quad = lane >> 4, l15 = lane & 15;
  const int mBase = blockIdx.x * 64;

  // staging lane map: lane i -> row i/4, LDS slot i%4; global chunk = slot ^ ((row>>1)&3)
  const int srow = lane >> 2;
  const int kc = (lane & 3) ^ ((srow >> 1) & 3);

  int am = mBase + w * 16 + srow;
  if (am >= NN) am = NN - 1;  // clamp (stores are guarded)
  const char* agp = (const char*)A + (size_t)am * (KA * 2) + kc * 16;
  const char* agx = (const char*)Xbf_in + (size_t)am * (DD * 2) + kc * 16;
  const char* bgp0 = (const char*)Bt + (size_t)(w * 64 + 0 + srow) * (KT * 2) + kc * 16;
  const char* bgp1 = (const char*)Bt + (size_t)(w * 64 + 16 + srow) * (KT * 2) + kc * 16;
  const char* bgp2 = (const char*)Bt + (size_t)(w * 64 + 32 + srow) * (KT * 2) + kc * 16;
  const char* bgp3 = (const char*)Bt + (size_t)(w * 64 + 48 + srow) * (KT * 2) + kc * 16;

  // per-wave LDS staging bases (wave-uniform; lane deposits at base + lane*16)
  char* const lA = sLDS + w * 1024;
  char* const lB = sLDS + 4096 + w * 4096;

  f32x4 acc[2][8];
#pragma unroll
  for (int i = 0; i < 2; ++i)
#pragma unroll
    for (int j = 0; j < 8; ++j) acc[i][j] = (f32x4){0.f, 0.f, 0.f, 0.f};

  const int aslot = (quad ^ ((l15 >> 1) & 3)) * 16;
  const char* const aBase = sLDS + (wm * 32 + l15) * 64 + aslot;          // + buf*GBUF + mt*1024
  const char* const bBase = sLDS + 4096 + (wn * 128 + l15) * 64 + aslot;  // + buf*GBUF + nt*1024

  auto STAGE = [&](int buf, int ts) {
    const int k0 = ts * 64;  // byte offset within logical K row
    char* la = lA + buf * GBUF;
    char* lb = lB + buf * GBUF;
    if (k0 < KA * 2) {  // cols 0..1023 from Abig (L3-resident)
      async16(agp + k0, la);
    } else {            // cols 1024..1279 from Xbf
      async16(agx + (k0 - KA * 2), la);
    }
    async16(bgp0 + k0, lb);
    async16(bgp1 + k0, lb + 1024);
    async16(bgp2 + k0, lb + 2048);
    async16(bgp3 + k0, lb + 3072);
  };

  auto COMPUTE = [&](int buf) {
    const char* aAddr = aBase + buf * GBUF;
    const char* bAddr = bBase + buf * GBUF;
    bf16x8 a0 = *(const bf16x8*)(aAddr + 0 * 1024);
    bf16x8 a1 = *(const bf16x8*)(aAddr + 1 * 1024);
#pragma unroll
    for (int nt = 0; nt < 8; ++nt) {
      bf16x8 b = *(const bf16x8*)(bAddr + nt * 1024);
      acc[0][nt] = __builtin_amdgcn_mfma_f32_16x16x32_bf16(a0, b, acc[0][nt], 0, 0, 0);
      acc[1][nt] = __builtin_amdgcn_mfma_f32_16x16x32_bf16(a1, b, acc[1][nt], 0, 0, 0);
    }
  };

  STAGE(0, 0);  // prologue: tiles 0,1 in flight (10 vmem ops/wave)
  STAGE(1, 1);
  int cb = 0, sb = 2;
  for (int t = 0; t < NTILE - 2; ++t) {
    STAGE(sb, t + 2);
    __builtin_amdgcn_sched_barrier(0);
    // retire tile t's 5 loads; tiles t+1, t+2 (10 ops) stay in flight
    asm volatile("s_waitcnt vmcnt(10)" ::: "memory");
    __builtin_amdgcn_s_barrier();
    __builtin_amdgcn_sched_barrier(0);
    COMPUTE(cb);
    cb = (cb + 1) & 3;
    sb = (sb + 1) & 3;
  }
  // peeled tail: no more staging; counts shrink 10 -> 5 -> 0
  asm volatile("s_waitcnt vmcnt(5)" ::: "memory");
  __builtin_amdgcn_s_barrier();
  __builtin_amdgcn_sched_barrier(0);
  COMPUTE(cb);
  cb = (cb + 1) & 3;
  asm volatile("s_waitcnt vmcnt(0)" ::: "memory");
  __builtin_amdgcn_s_barrier();
  __builtin_amdgcn_sched_barrier(0);
  COMPUTE(cb);

  // all buffers fully consumed; no loads in flight -> sLDS reusable as sRed
  __syncthreads();

  // ---- epilogue: bias, LN (full 256-wide rows in-block), ELU, residual ----
  float bv[8], gv[8], bev[8];
#pragma unroll
  for (int nt = 0; nt < 8; ++nt) {
    int n = wn * 128 + nt * 16 + l15;
    bv[nt] = bias[n];
    gv[nt] = gamma[n];
    bev[nt] = beta[n];
  }

#pragma unroll
  for (int mt = 0; mt < 2; ++mt) {
#pragma unroll
    for (int reg = 0; reg < 4; ++reg) {
      float s = 0.f, q = 0.f;
#pragma unroll
      for (int nt = 0; nt < 8; ++nt) {
        float v = acc[mt][nt][reg] + bv[nt];
        acc[mt][nt][reg] = v;
        s += v;
        q += v * v;
      }
#pragma unroll
      for (int d = 1; d < 16; d <<= 1) {
        s += __shfl_xor(s, d, 64);
        q += __shfl_xor(q, d, 64);
      }
      if (l15 == 0) {
        int row = wm * 32 + mt * 16 + quad * 4 + reg;
        sRed[row][wn * 2] = s;
        sRed[row][wn * 2 + 1] = q;
      }
    }
  }
  __syncthreads();

#pragma unroll
  for (int mt = 0; mt < 2; ++mt) {
#pragma unroll
    for (int reg = 0; reg < 4; ++reg) {
      int row = wm * 32 + mt * 16 + quad * 4 + reg;
      float ts = sRed[row][0] + sRed[row][2];
      float tq = sRed[row][1] + sRed[row][3];
      float mean = ts * (1.0f / 256.0f);
      float var = tq * (1.0f / 256.0f) - mean * mean;
      float rstd = rsqrtf(var + 1e-5f);
      int m = mBase + row;
      if (m < NN) {
#pragma unroll
        for (int nt = 0; nt < 8; ++nt) {
          int n = wn * 128 + nt * 16 + l15;
          float v = (acc[mt][nt][reg] - mean) * rstd * gv[nt] + bev[nt];
          v = v > 0.0f ? v : (__expf(v) - 1.0f);
          // fp32 X streams are read/written exactly once per layer: NT so the
          // 2x51MB streams don't evict Abig/Xbf from L3
          float res = v + __builtin_nontemporal_load(&Xin[(size_t)m * 256 + n]);
          __builtin_nontemporal_store(res, &Xout[(size_t)m * 256 + n]);
          Xbf_out[(size_t)m * 256 + n] = __float2bfloat16(res);
        }
      }
    }
  }
}

// ---------------- host side ----------------

extern "C" void kernel_launch(void* const* d_in, const int* in_sizes, int n_in,
                              void* d_out, int out_size, void* d_ws, size_t ws_size,
                              hipStream_t stream) {
  const float* X0 = (const float*)d_in[0];
  const float* weights = (const float*)d_in[1];
  const float* roots = (const float*)d_in[2];
  const float* biases = (const float*)d_in[3];
  const float* ln_g = (const float*)d_in[4];
  const float* ln_b = (const float*)d_in[5];
  const int* eidx = (const int*)d_in[6];
  const int* etyp = (const int*)d_in[7];
  float* out = (float*)d_out;

  char* ws = (char*)d_ws;
  size_t off = 0;
  auto alloc = [&](size_t bytes) -> char* {
    char* p = ws + off;
    off = (off + bytes + 255) & ~(size_t)255;
    return p;
  };
  __hip_bfloat16* Abig = (__hip_bfloat16*)alloc((size_t)NN * KA * 2);          // 102.4 MB
  __hip_bfloat16* WbigT = (__hip_bfloat16*)alloc((size_t)NL * DD * KT * 2);    // 2.6 MB
  float* Xb0 = (float*)alloc((size_t)NN * DD * 4);                              // 51.2 MB
  float* Xb1 = (float*)alloc((size_t)NN * DD * 4);                              // 51.2 MB
  __hip_bfloat16* Xbf0 = (__hip_bfloat16*)alloc((size_t)NN * DD * 2);           // 25.6 MB
  __hip_bfloat16* Xbf1 = (__hip_bfloat16*)alloc((size_t)NN * DD * 2);           // 25.6 MB
  int* cntNR = (int*)alloc((size_t)NN * 4 * 4);
  int* offs = (int*)alloc((size_t)(NN + 1) * 4);
  int* cursor = (int*)alloc((size_t)NN * 4);
  uint32_t* packed = (uint32_t*)alloc((size_t)NE * 4);
  int* bsum = (int*)alloc(256 * 4);
  int* boff = (int*)alloc(256 * 4);
  (void)ws_size; (void)in_sizes; (void)n_in; (void)out_size;

  (void)hipMemsetAsync(cntNR, 0, (size_t)NN * 16, stream);
  k_hist<<<(NE + 255) / 256, 256, 0, stream>>>(eidx, etyp, cntNR);
  const int NB = (NN + 255) / 256;  // 196
  k_scan1<<<NB, 256, 0, stream>>>(cntNR, offs, bsum);
  k_scan2<<<1, 256, 0, stream>>>(bsum, boff, NB);
  k_scan3<<<NB, 256, 0, stream>>>(offs, boff, cursor);
  k_scatter<<<(NE + 255) / 256, 256, 0, stream>>>(eidx, etyp, cursor, packed);
  k_wconv<<<(NL * DD * KT + 255) / 256, 256, 0, stream>>>(weights, roots, WbigT);
  k_cast<<<(NN * 64 + 255) / 256, 256, 0, stream>>>(X0, Xbf0);

  const float* Xin = X0;
  for (int l = 0; l < NL; ++l) {
    float* Xout = (l == NL - 1) ? out : ((l & 1) ? Xb1 : Xb0);
    const __hip_bfloat16* Xbin = (l & 1) ? Xbf1 : Xbf0;
    __hip_bfloat16* Xbout = (l & 1) ? Xbf0 : Xbf1;
    k_agg<<<(NN * 64 + 255) / 256, 256, 0, stream>>>(Xbin, packed, offs, cntNR, Abig);
    k_gemm<<<(NN + 63) / 64, 256, 0, stream>>>(Abig, Xbin,
                                               WbigT + (size_t)l * DD * KT,
                                               biases + (size_t)l * DD,
                                               ln_g + (size_t)l * DD,
                                               ln_b + (size_t)l * DD, Xin, Xout, Xbout);
    Xin = Xout;
  }
}

// Round 3
// 800.490 us; speedup vs baseline: 1.2129x; 1.0824x over previous
//
#include <hip/hip_runtime.h>
#include <hip/hip_bf16.h>
#include <stdint.h>

#define NN 50000
#define NE 800000
#define DD 256
#define NL 4
#define NRL 4
#define KT 1280  // NRL*DD + DD (logical K of the fused GEMM)
#define KA 1024  // NRL*DD (columns stored in Abig; root block comes from Xbf)
#define NMT 782  // ceil(NN/64) m-tiles
#define MTB 131072  // bytes per A m-tile: 32 k-tiles * 64 rows * 64 B

typedef float f32x4 __attribute__((ext_vector_type(4)));
typedef __bf16 bf16x8 __attribute__((ext_vector_type(8)));
typedef __bf16 bf16x4 __attribute__((ext_vector_type(4)));
typedef unsigned short u16x4 __attribute__((ext_vector_type(4)));

static __device__ __forceinline__ unsigned short f2bf(float f) {
  __bf16 h = (__bf16)f;
  return __builtin_bit_cast(unsigned short, h);
}

static __device__ __forceinline__ u16x4 pk4(f32x4 v) {
  u16x4 o;
  o.x = f2bf(v.x); o.y = f2bf(v.y); o.z = f2bf(v.z); o.w = f2bf(v.w);
  return o;
}

static __device__ __forceinline__ void async16(const void* g, void* l) {
  __builtin_amdgcn_global_load_lds(
      (const __attribute__((address_space(1))) unsigned int*)g,
      (__attribute__((address_space(3))) unsigned int*)l, 16, 0, 0);
}

// ---------------- edge preprocessing (once per call) ----------------

__global__ __launch_bounds__(256) void k_hist(const int* __restrict__ ei,
                                              const int* __restrict__ et,
                                              int* __restrict__ cntNR) {
  int e = blockIdx.x * 256 + threadIdx.x;
  if (e >= NE) return;
  int dst = ei[NE + e];
  int r = et[e];
  atomicAdd(&cntNR[dst * 4 + r], 1);
}

__global__ __launch_bounds__(256) void k_scan1(const int* __restrict__ cntNR,
                                               int* __restrict__ offs,
                                               int* __restrict__ bsum) {
  __shared__ int sd[256];
  const int t = threadIdx.x;
  const int n = blockIdx.x * 256 + t;
  int deg = 0;
  if (n < NN) {
    const int* c = cntNR + n * 4;
    deg = c[0] + c[1] + c[2] + c[3];
  }
  sd[t] = deg;
  __syncthreads();
  int val = deg;
  for (int d = 1; d < 256; d <<= 1) {
    int other = (t >= d) ? sd[t - d] : 0;
    __syncthreads();
    val += other;
    sd[t] = val;
    __syncthreads();
  }
  if (n < NN) offs[n] = val - deg;  // exclusive
  if (t == 255) bsum[blockIdx.x] = val;
}

__global__ __launch_bounds__(256) void k_scan2(const int* __restrict__ bsum,
                                               int* __restrict__ boff, int nb) {
  __shared__ int sd[256];
  const int t = threadIdx.x;
  int v = (t < nb) ? bsum[t] : 0;
  sd[t] = v;
  __syncthreads();
  int val = v;
  for (int d = 1; d < 256; d <<= 1) {
    int other = (t >= d) ? sd[t - d] : 0;
    __syncthreads();
    val += other;
    sd[t] = val;
    __syncthreads();
  }
  boff[t] = val - v;  // exclusive
}

__global__ __launch_bounds__(256) void k_scan3(int* __restrict__ offs,
                                               const int* __restrict__ boff,
                                               int* __restrict__ cursor) {
  int n = blockIdx.x * 256 + threadIdx.x;
  if (n < NN) {
    int o = offs[n] + boff[blockIdx.x];
    offs[n] = o;
    cursor[n] = o;
  }
  if (n == 0) offs[NN] = NE;
}

__global__ __launch_bounds__(256) void k_scatter(const int* __restrict__ ei,
                                                 const int* __restrict__ et,
                                                 int* __restrict__ cursor,
                                                 uint32_t* __restrict__ packed) {
  int e = blockIdx.x * 256 + threadIdx.x;
  if (e >= NE) return;
  int src = ei[e];
  int dst = ei[NE + e];
  int r = et[e];
  int pos = atomicAdd(&cursor[dst], 1);
  packed[pos] = (uint32_t)src | ((uint32_t)r << 16);  // src < 65536 ok
}

// Build tiled+pre-swizzled B: WbigT[l][kt=0..39][row=0..255][slot=0..3][e=0..7] bf16,
// content at (kt,row,slot,e) = B^T[row][k] with k = kt*32 + (slot^((row>>1)&3))*8 + e,
// where B^T[o][k] = (k<1024) ? weights[l][k>>8][k&255][o] : roots[l][k-1024][o].
// This makes every k_gemm B staging load a CONTIGUOUS 1KB burst while producing
// byte-identical LDS content to the old scattered-row staging.
__global__ __launch_bounds__(256) void k_wconv(const float* __restrict__ weights,
                                               const float* __restrict__ roots,
                                               __hip_bfloat16* __restrict__ WbigT) {
  int idx = blockIdx.x * 256 + threadIdx.x;
  if (idx >= NL * DD * KT) return;  // 1,310,720 = 4*40*256*32
  int l = idx / 327680;             // 40*256*32
  int rem = idx - l * 327680;
  int kt = rem / 8192;              // 256*32
  int rem2 = rem - kt * 8192;
  int row = rem2 >> 5;
  int q = rem2 & 31;
  int s = q >> 3, e = q & 7;
  int k = kt * 32 + ((s ^ ((row >> 1) & 3)) << 3) + e;
  float v;
  if (k < KA) {
    int r = k >> 8, i = k & 255;
    v = weights[(((size_t)(l * NRL + r) * DD) + i) * DD + row];
  } else {
    int i = k - KA;
    v = roots[((size_t)l * DD + i) * DD + row];
  }
  WbigT[idx] = __float2bfloat16(v);
}

// one-time fp32 -> bf16 cast of the input embedding (4 elems/thread)
__global__ __launch_bounds__(256) void k_cast(const float* __restrict__ X,
                                              __hip_bfloat16* __restrict__ Xbf) {
  int i = blockIdx.x * 256 + threadIdx.x;
  if (i >= NN * 64) return;
  const f32x4* Xv = (const f32x4*)X;
  ((u16x4*)Xbf)[i] = pk4(Xv[i]);
}

// ---------------- per-layer aggregation: one wave per node, pipelined bf16 gather ------
// Output layout is the GEMM-staging-tiled form: Abig[mtile][kt=0..31][row=0..63][slot][8B]
// content at (kt,row,slot) = A[node=mtile*64+row][k-bytes kt*64 + (slot^((row>>1)&3))*16].

__global__ __launch_bounds__(256) void k_agg(const __hip_bfloat16* __restrict__ Xbf,
                                             const uint32_t* __restrict__ packed,
                                             const int* __restrict__ offs,
                                             const int* __restrict__ cntNR,
                                             __hip_bfloat16* __restrict__ Abig) {
  const int wid = (blockIdx.x * 256 + threadIdx.x) >> 6;
  const int lane = threadIdx.x & 63;
  if (wid >= NN) return;
  const int beg = offs[wid];
  const int end = offs[wid + 1];
  const bf16x4* __restrict__ Xv = (const bf16x4*)Xbf;

  f32x4 a0 = {0.f, 0.f, 0.f, 0.f}, a1 = a0, a2 = a0, a3 = a0;

  // depth-8 software pipeline: 8 packed loads, then 8 row-gathers in flight,
  // then accumulate (r is wave-uniform -> scalar branch)
  for (int e = beg; e < end; e += 8) {
    uint32_t pv[8];
    bf16x4 vv[8];
#pragma unroll
    for (int i = 0; i < 8; ++i) {
      int ee = e + i;
      ee = (ee < end) ? ee : (end - 1);
      pv[i] = packed[ee];
    }
#pragma unroll
    for (int i = 0; i < 8; ++i) {
      vv[i] = Xv[(int)(pv[i] & 0xFFFFu) * 64 + lane];
    }
    const int nv = end - e;
#pragma unroll
    for (int i = 0; i < 8; ++i) {
      if (i < nv) {
        int r = (int)(pv[i] >> 16);
        f32x4 v = {(float)vv[i][0], (float)vv[i][1], (float)vv[i][2], (float)vv[i][3]};
        if (r == 0) a0 += v;
        else if (r == 1) a1 += v;
        else if (r == 2) a2 += v;
        else a3 += v;
      }
    }
  }

  const int* c = cntNR + wid * 4;
  int c0 = c[0], c1 = c[1], c2 = c[2], c3 = c[3];
  float s0 = 1.0f / (float)(c0 > 1 ? c0 : 1);
  float s1 = 1.0f / (float)(c1 > 1 ? c1 : 1);
  float s2 = 1.0f / (float)(c2 > 1 ? c2 : 1);
  float s3 = 1.0f / (float)(c3 > 1 ? c3 : 1);

  // Tiled+swizzled scatter store. Lane holds dims [lane*4, lane*4+4) (8 B) of each
  // relation.  k-byte = r*512 + lane*8 -> kt = r*8 + (lane>>3); 16B-slot within the
  // 64B chunk = (lane>>1)&3, swizzled by f=(row>>1)&3; byte-in-slot = (lane&1)*8.
  {
    const int row = wid & 63;
    const int fsw = (row >> 1) & 3;
    char* Ab = (char*)Abig + (size_t)(wid >> 6) * MTB + (size_t)(lane >> 3) * 4096 +
               row * 64 + ((((lane >> 1) & 3) ^ fsw) << 4) + (lane & 1) * 8;
    *(u16x4*)(Ab + 0 * 32768) = pk4(a0 * s0);  // r: kt += 8 -> +32768 B
    *(u16x4*)(Ab + 1 * 32768) = pk4(a1 * s1);
    *(u16x4*)(Ab + 2 * 32768) = pk4(a2 * s2);
    *(u16x4*)(Ab + 3 * 32768) = pk4(a3 * s3);
  }
}

// ---------------- GEMM + bias + LayerNorm + ELU + residual (+ bf16 X for next layer) ----
// C[m, n] = [Abig | Xbf][m, 0:1280] @ WbigT[n, 0:1280]^T ; BM=64, BN=256, BK=32
// 4 waves in 2x2: each wave 32 rows x 128 cols = 2x8 MFMA tiles.
// A (kt<32) and B staging loads are CONTIGUOUS 1KB bursts from the tiled buffers;
// only the 8 root tiles (kt>=32, from row-major Xbf) remain scattered.
// 4-buffer LDS pipeline, depth-2 prefetch, counted vmcnt (T3+T4):
//   steady state tiles t,t+1,t+2 in flight (15 ops/wave); vmcnt(10) retires tile t.
//   Peeled tail drains 10 -> 5 -> 0.  Per wave per tile: 1 A + 4 B = 5 vmem ops.

#define GBUF 20480  // per-buffer LDS bytes: A 4KB + B 16KB
#define NTILE 40    // KT*2/64

__global__ __launch_bounds__(256, 2) void k_gemm(const __hip_bfloat16* __restrict__ A,
                                                 const __hip_bfloat16* __restrict__ Xbf_in,
                                                 const __hip_bfloat16* __restrict__ Bt,
                                                 const float* __restrict__ bias,
                                                 const float* __restrict__ gamma,
                                                 const float* __restrict__ beta,
                                                 const float* __restrict__ Xin,
                                                 float* __restrict__ Xout,
                                                 __hip_bfloat16* __restrict__ Xbf_out) {
  __shared__ __align__(16) char sLDS[4 * GBUF];  // 80KB: 4 x (A 64x64B | B 256x64B)
  float(*sRed)[4] = (float(*)[4])sLDS;           // overlay, used after the main loop

  const int tid = threadIdx.x;
  const int w = tid >> 6;
  const int lane = tid & 63;
  const int wm = w >> 1, wn = w & 1;
  const int quad = lane >> 4, l15 = lane & 15;
  const int mBase = blockIdx.x * 64;

  // root-tile (scattered) staging lane map, identical to the old path
  const int srow = lane >> 2;
  const int kc = (lane & 3) ^ ((srow >> 1) & 3);
  int am = mBase + w * 16 + srow;
  if (am >= NN) am = NN - 1;  // clamp (stores are guarded)
  const char* agx = (const char*)Xbf_in + (size_t)am * (DD * 2) + kc * 16;

  // tiled contiguous sources
  const char* agp = (const char*)A + (size_t)blockIdx.x * MTB + w * 1024 + lane * 16;
  const char* bgp = (const char*)Bt + w * 4096 + lane * 16;

  // per-wave LDS staging bases (wave-uniform; lane deposits at base + lane*16)
  char* const lA = sLDS + w * 1024;
  char* const lB = sLDS + 4096 + w * 4096;

  f32x4 acc[2][8];
#pragma unroll
  for (int i = 0; i < 2; ++i)
#pragma unroll
    for (int j = 0; j < 8; ++j) acc[i][j] = (f32x4){0.f, 0.f, 0.f, 0.f};

  const int aslot = (quad ^ ((l15 >> 1) & 3)) * 16;
  const char* const aBase = sLDS + (wm * 32 + l15) * 64 + aslot;          // + buf*GBUF + mt*1024
  const char* const bBase = sLDS + 4096 + (wn * 128 + l15) * 64 + aslot;  // + buf*GBUF + nt*1024

  auto STAGE = [&](int buf, int ts) {
    char* la = lA + buf * GBUF;
    char* lb = lB + buf * GBUF;
    if (ts < 32) {
      async16(agp + (size_t)ts * 4096, la);     // contiguous 1KB
    } else {
      async16(agx + (ts - 32) * 64, la);        // root tiles: scattered rows of Xbf
    }
    const char* bt = bgp + (size_t)ts * 16384;  // contiguous 4x1KB
    async16(bt, lb);
    async16(bt + 1024, lb + 1024);
    async16(bt + 2048, lb + 2048);
    async16(bt + 3072, lb + 3072);
  };

  auto COMPUTE = [&](int buf) {
    const char* aAddr = aBase + buf * GBUF;
    const char* bAddr = bBase + buf * GBUF;
    bf16x8 a0 = *(const bf16x8*)(aAddr + 0 * 1024);
    bf16x8 a1 = *(const bf16x8*)(aAddr + 1 * 1024);
#pragma unroll
    for (int nt = 0; nt < 8; ++nt) {
      bf16x8 b = *(const bf16x8*)(bAddr + nt * 1024);
      acc[0][nt] = __builtin_amdgcn_mfma_f32_16x16x32_bf16(a0, b, acc[0][nt], 0, 0, 0);
      acc[1][nt] = __builtin_amdgcn_mfma_f32_16x16x32_bf16(a1, b, acc[1][nt], 0, 0, 0);
    }
  };

  STAGE(0, 0);  // prologue: tiles 0,1 in flight (10 vmem ops/wave)
  STAGE(1, 1);
  int cb = 0, sb = 2;
  for (int t = 0; t < NTILE - 2; ++t) {
    STAGE(sb, t + 2);
    __builtin_amdgcn_sched_barrier(0);
    // retire tile t's 5 loads; tiles t+1, t+2 (10 ops) stay in flight
    asm volatile("s_waitcnt vmcnt(10)" ::: "memory");
    __builtin_amdgcn_s_barrier();
    __builtin_amdgcn_sched_barrier(0);
    COMPUTE(cb);
    cb = (cb + 1) & 3;
    sb = (sb + 1) & 3;
  }
  // peeled tail: no more staging; counts shrink 10 -> 5 -> 0
  asm volatile("s_waitcnt vmcnt(5)" ::: "memory");
  __builtin_amdgcn_s_barrier();
  __builtin_amdgcn_sched_barrier(0);
  COMPUTE(cb);
  cb = (cb + 1) & 3;
  asm volatile("s_waitcnt vmcnt(0)" ::: "memory");
  __builtin_amdgcn_s_barrier();
  __builtin_amdgcn_sched_barrier(0);
  COMPUTE(cb);

  // all buffers fully consumed; no loads in flight -> sLDS reusable as sRed
  __syncthreads();

  // ---- epilogue: bias, LN (full 256-wide rows in-block), ELU, residual ----
  float bv[8], gv[8], bev[8];
#pragma unroll
  for (int nt = 0; nt < 8; ++nt) {
    int n = wn * 128 + nt * 16 + l15;
    bv[nt] = bias[n];
    gv[nt] = gamma[n];
    bev[nt] = beta[n];
  }

#pragma unroll
  for (int mt = 0; mt < 2; ++mt) {
#pragma unroll
    for (int reg = 0; reg < 4; ++reg) {
      float s = 0.f, q = 0.f;
#pragma unroll
      for (int nt = 0; nt < 8; ++nt) {
        float v = acc[mt][nt][reg] + bv[nt];
        acc[mt][nt][reg] = v;
        s += v;
        q += v * v;
      }
#pragma unroll
      for (int d = 1; d < 16; d <<= 1) {
        s += __shfl_xor(s, d, 64);
        q += __shfl_xor(q, d, 64);
      }
      if (l15 == 0) {
        int row = wm * 32 + mt * 16 + quad * 4 + reg;
        sRed[row][wn * 2] = s;
        sRed[row][wn * 2 + 1] = q;
      }
    }
  }
  __syncthreads();

#pragma unroll
  for (int mt = 0; mt < 2; ++mt) {
#pragma unroll
    for (int reg = 0; reg < 4; ++reg) {
      int row = wm * 32 + mt * 16 + quad * 4 + reg;
      float ts = sRed[row][0] + sRed[row][2];
      float tq = sRed[row][1] + sRed[row][3];
      float mean = ts * (1.0f / 256.0f);
      float var = tq * (1.0f / 256.0f) - mean * mean;
      float rstd = rsqrtf(var + 1e-5f);
      int m = mBase + row;
      if (m < NN) {
#pragma unroll
        for (int nt = 0; nt < 8; ++nt) {
          int n = wn * 128 + nt * 16 + l15;
          float v = (acc[mt][nt][reg] - mean) * rstd * gv[nt] + bev[nt];
          v = v > 0.0f ? v : (__expf(v) - 1.0f);
          // fp32 X streams are read/written exactly once per layer: NT so the
          // 2x51MB streams don't evict Abig/Xbf from L3
          float res = v + __builtin_nontemporal_load(&Xin[(size_t)m * 256 + n]);
          __builtin_nontemporal_store(res, &Xout[(size_t)m * 256 + n]);
          Xbf_out[(size_t)m * 256 + n] = __float2bfloat16(res);
        }
      }
    }
  }
}

// ---------------- host side ----------------

extern "C" void kernel_launch(void* const* d_in, const int* in_sizes, int n_in,
                              void* d_out, int out_size, void* d_ws, size_t ws_size,
                              hipStream_t stream) {
  const float* X0 = (const float*)d_in[0];
  const float* weights = (const float*)d_in[1];
  const float* roots = (const float*)d_in[2];
  const float* biases = (const float*)d_in[3];
  const float* ln_g = (const float*)d_in[4];
  const float* ln_b = (const float*)d_in[5];
  const int* eidx = (const int*)d_in[6];
  const int* etyp = (const int*)d_in[7];
  float* out = (float*)d_out;

  char* ws = (char*)d_ws;
  size_t off = 0;
  auto alloc = [&](size_t bytes) -> char* {
    char* p = ws + off;
    off = (off + bytes + 255) & ~(size_t)255;
    return p;
  };
  __hip_bfloat16* Abig = (__hip_bfloat16*)alloc((size_t)NMT * MTB);             // 102.5 MB tiled
  __hip_bfloat16* WbigT = (__hip_bfloat16*)alloc((size_t)NL * DD * KT * 2);     // 2.6 MB tiled
  float* Xb0 = (float*)alloc((size_t)NN * DD * 4);                              // 51.2 MB
  float* Xb1 = (float*)alloc((size_t)NN * DD * 4);                              // 51.2 MB
  __hip_bfloat16* Xbf0 = (__hip_bfloat16*)alloc((size_t)NN * DD * 2);           // 25.6 MB
  __hip_bfloat16* Xbf1 = (__hip_bfloat16*)alloc((size_t)NN * DD * 2);           // 25.6 MB
  int* cntNR = (int*)alloc((size_t)NN * 4 * 4);
  int* offs = (int*)alloc((size_t)(NN + 1) * 4);
  int* cursor = (int*)alloc((size_t)NN * 4);
  uint32_t* packed = (uint32_t*)alloc((size_t)NE * 4);
  int* bsum = (int*)alloc(256 * 4);
  int* boff = (int*)alloc(256 * 4);
  (void)ws_size; (void)in_sizes; (void)n_in; (void)out_size;

  (void)hipMemsetAsync(cntNR, 0, (size_t)NN * 16, stream);
  // zero the tail m-tile of Abig once per call: rows 16..63 of m-tile 781 are never
  // written by k_agg (nodes >= NN) but are read by the last k_gemm block.
  (void)hipMemsetAsync((char*)Abig + (size_t)(NMT - 1) * MTB, 0, MTB, stream);
  k_hist<<<(NE + 255) / 256, 256, 0, stream>>>(eidx, etyp, cntNR);
  const int NB = (NN + 255) / 256;  // 196
  k_scan1<<<NB, 256, 0, stream>>>(cntNR, offs, bsum);
  k_scan2<<<1, 256, 0, stream>>>(bsum, boff, NB);
  k_scan3<<<NB, 256, 0, stream>>>(offs, boff, cursor);
  k_scatter<<<(NE + 255) / 256, 256, 0, stream>>>(eidx, etyp, cursor, packed);
  k_wconv<<<(NL * DD * KT + 255) / 256, 256, 0, stream>>>(weights, roots, WbigT);
  k_cast<<<(NN * 64 + 255) / 256, 256, 0, stream>>>(X0, Xbf0);

  const float* Xin = X0;
  for (int l = 0; l < NL; ++l) {
    float* Xout = (l == NL - 1) ? out : ((l & 1) ? Xb1 : Xb0);
    const __hip_bfloat16* Xbin = (l & 1) ? Xbf1 : Xbf0;
    __hip_bfloat16* Xbout = (l & 1) ? Xbf0 : Xbf1;
    k_agg<<<(NN * 64 + 255) / 256, 256, 0, stream>>>(Xbin, packed, offs, cntNR, Abig);
    k_gemm<<<(NN + 63) / 64, 256, 0, stream>>>(Abig, Xbin,
                                               WbigT + (size_t)l * DD * KT,
                                               biases + (size_t)l * DD,
                                               ln_g + (size_t)l * DD,
                                               ln_b + (size_t)l * DD, Xin, Xout, Xbout);
    Xin = Xout;
  }
}